// Round 12
// baseline (151.352 us; speedup 1.0000x reference)
//
#include <hip/hip_runtime.h>
#include <math.h>

// Problem constants (match reference)
#define MB 8      // batch
#define MM 384    // checks
#define NN 1536   // variables
#define LL 20     // layers
#define RW 8      // row weight of H
#define HE 4      // edges per thread (half row)
#define NE (MM*RW)  // 3072 edges
#define NT 768    // bp block size (2 threads per check row)
#define VP 12     // max column degree supported (validated R10/R11: absmax=0)
#define VG 3      // VP/4 float4 groups

// ---------------------------------------------------------------------------
// Zero kernel: clears the CSC weight tables + column counters + out scalar.
// (ws is re-poisoned to 0xAA before every timed launch.)
// ---------------------------------------------------------------------------
__global__ void zero_kernel(float* __restrict__ p, int n, float* __restrict__ out) {
    int i = blockIdx.x * blockDim.x + threadIdx.x;
    int stride = gridDim.x * blockDim.x;
    for (; i < n; i += stride) p[i] = 0.0f;
    if (blockIdx.x == 0 && threadIdx.x == 0) out[0] = 0.0f;
}

// ---------------------------------------------------------------------------
// Fused setup: one block (256 thr = 4 waves) per check row.
//  4-wave ballot scan of H row m -> RW column indices; assign each edge its
//  CSC position via global column counters; fill the TRANSPOSED weight
//  tables wde_vT[l][jg][n][ji] and marg_vT[jg][n][ji] (padding stays 0 from
//  zero_kernel), plus the per-edge base_e pre-gather.
// ---------------------------------------------------------------------------
__global__ __launch_bounds__(256) void setup_kernel(
    const float* __restrict__ H,
    const float* __restrict__ llrs,
    const float* __restrict__ w_llr,
    const float* __restrict__ w_de,
    const float* __restrict__ marg_de,
    int*   __restrict__ col_pack,
    float* __restrict__ base_e,
    float* __restrict__ wde_vT,
    float* __restrict__ marg_vT,
    int*   __restrict__ gcnt) {
    const int m = blockIdx.x;
    const int t = threadIdx.x;
    const int w = t >> 6, lane = t & 63;
    __shared__ int s_qcol[4][RW];
    __shared__ int s_qcnt[4];
    __shared__ int s_col[RW];
    __shared__ int s_pos[RW];

    const float* row = H + (size_t)m * NN;
    int count = 0;
    for (int c0 = w * 384; c0 < (w + 1) * 384; c0 += 64) {
        float v = row[c0 + lane];
        unsigned long long mask = __ballot(v != 0.0f);
        if (v != 0.0f) {
            int pos = count + (int)__popcll(mask & ((1ull << lane) - 1ull));
            if (pos < RW) s_qcol[w][pos] = c0 + lane;
        }
        count += (int)__popcll(mask);
    }
    if (lane == 0) s_qcnt[w] = (count < RW) ? count : RW;
    __syncthreads();
    if (t == 0) {
        int off = 0;
        for (int q = 0; q < 4; ++q)
            for (int i = 0; i < s_qcnt[q]; ++i) {
                if (off < RW) s_col[off] = s_qcol[q][i];
                ++off;
            }
    }
    __syncthreads();

    if (t < RW) {
        int c = s_col[t];
        int pos = atomicAdd(&gcnt[c], 1);
        if (pos >= VP) pos = VP - 1;   // clamp (validated: never hit)
        s_pos[t] = pos;
        col_pack[m * RW + t] = c | (pos << 16);
        marg_vT[((pos >> 2) * NN + c) * 4 + (pos & 3)] = marg_de[m * NN + c];
    }
    __syncthreads();

    // 20 layers x 8 edges per row
    for (int idx = t; idx < LL * RW; idx += 256) {
        int l = idx >> 3;
        int k = idx & 7;
        int c = s_col[k];
        int pos = s_pos[k];
        wde_vT[((l * VG + (pos >> 2)) * NN + c) * 4 + (pos & 3)] =
            w_de[(size_t)l * MM * NN + (size_t)m * NN + c];
        base_e[l * NE + m * RW + k] = llrs[c] * w_llr[l * NN + c];
    }
}

// ---------------------------------------------------------------------------
// Main BP kernel: 8 blocks, 768 threads = 2 per check row (4 edges each).
// Zero atomics; CSC-padded exchange array s_cN[(jg*NN+n)*4+ji] holds nm.
// Per layer:
//   top:  each variable-owner does 3 unconditional ds_read_b128 per var and
//         FMAs against register-held transposed weights (wde for S, marg for
//         beliefs); plain-writes s_S; deferred loss for l-1.   [barrier A]
//   edge: check-node update reads s_S[col], writes nm to its fixed CSC slot
//         (4 scalar ds_writes).                                [barrier B]
// Padding slots of s_cN are never written (stay 0) -> contribute nothing.
// ---------------------------------------------------------------------------
__global__ __launch_bounds__(NT) void bp_kernel(
    const float* __restrict__ synd,       // (B,M,1)
    const float* __restrict__ errors,     // (B,N)
    const float* __restrict__ llrs,       // (N)
    const float* __restrict__ marg_llr,   // (N)
    const float* __restrict__ res_w,      // (L)
    const float* __restrict__ rhos,       // (L)
    const int*   __restrict__ col_pack,   // (E)  c | pos<<16
    const float* __restrict__ base_e_g,   // (L,E)
    const float* __restrict__ wde_vT,     // (L,VG,N,4)
    const float* __restrict__ marg_vT,    // (VG,N,4)
    float* __restrict__ out) {

    __shared__ float s_cN[NN * VP];       // 72 KB  edge messages, CSC-padded
    __shared__ float s_S[NN];             // 6 KB   variable sums
    __shared__ float s_rw[LL];
    __shared__ float s_rho[LL];
    __shared__ float s_red[12];

    const int b = blockIdx.x;
    const int t = threadIdx.x;
    const int m = t >> 1;        // check row; edges owned: e = t*HE + k

    // ---- per-edge register state ----
    int col[HE], esl[HE];
    {
        const int4 cp = ((const int4*)col_pack)[t];
        int v[HE] = {cp.x, cp.y, cp.z, cp.w};
        #pragma unroll
        for (int k = 0; k < HE; ++k) {
            int c = v[k] & 0xFFFF, pos = v[k] >> 16;
            col[k] = c;
            esl[k] = ((pos >> 2) * NN + c) * 4 + (pos & 3);
        }
    }
    float msg[HE] = {0.0f, 0.0f, 0.0f, 0.0f};
    const float sgn = 1.0f - 2.0f * synd[b * MM + m];

    float bias[2], omeg[2];
    #pragma unroll
    for (int i = 0; i < 2; ++i) {
        int n = t + i * NT;
        bias[i] = llrs[n] * marg_llr[n];
        omeg[i] = 1.0f - errors[b * NN + n];
    }

    // ---- register-held transposed weights for owned variables t, t+NT ----
    float mg0[VP], mg1[VP];
    #pragma unroll
    for (int jg = 0; jg < VG; ++jg) {
        float4 a = ((const float4*)marg_vT)[jg * NN + t];
        mg0[jg*4+0] = a.x; mg0[jg*4+1] = a.y; mg0[jg*4+2] = a.z; mg0[jg*4+3] = a.w;
        float4 c4 = ((const float4*)marg_vT)[jg * NN + t + NT];
        mg1[jg*4+0] = c4.x; mg1[jg*4+1] = c4.y; mg1[jg*4+2] = c4.z; mg1[jg*4+3] = c4.w;
    }
    float wc0[VP], wc1[VP], wn0[VP], wn1[VP];
    #pragma unroll
    for (int jg = 0; jg < VG; ++jg) {          // layer 0
        float4 a = ((const float4*)wde_vT)[jg * NN + t];
        wc0[jg*4+0] = a.x; wc0[jg*4+1] = a.y; wc0[jg*4+2] = a.z; wc0[jg*4+3] = a.w;
        float4 c4 = ((const float4*)wde_vT)[jg * NN + t + NT];
        wc1[jg*4+0] = c4.x; wc1[jg*4+1] = c4.y; wc1[jg*4+2] = c4.z; wc1[jg*4+3] = c4.w;
    }
    float bc[HE], bn[HE];
    {
        const float4 bp4 = ((const float4*)base_e_g)[t];   // layer 0
        bc[0] = bp4.x; bc[1] = bp4.y; bc[2] = bp4.z; bc[3] = bp4.w;
    }

    // ---- zero the exchange array (padding slots stay 0 forever) ----
    #pragma unroll
    for (int j = 0; j < 6; ++j)
        ((float4*)s_cN)[j * NT + t] = make_float4(0.f, 0.f, 0.f, 0.f);
    if (t < LL) { s_rw[t] = res_w[t]; s_rho[t] = rhos[t]; }

    float loss = 0.0f;
    __syncthreads();

    for (int l = 0; l < LL; ++l) {
        // prefetch next layer's wde_vT and base_e
        {
            int lb = (l + 1 < LL) ? (l + 1) : (LL - 1);
            #pragma unroll
            for (int jg = 0; jg < VG; ++jg) {
                float4 a = ((const float4*)wde_vT)[(lb * VG + jg) * NN + t];
                wn0[jg*4+0] = a.x; wn0[jg*4+1] = a.y; wn0[jg*4+2] = a.z; wn0[jg*4+3] = a.w;
                float4 c4 = ((const float4*)wde_vT)[(lb * VG + jg) * NN + t + NT];
                wn1[jg*4+0] = c4.x; wn1[jg*4+1] = c4.y; wn1[jg*4+2] = c4.z; wn1[jg*4+3] = c4.w;
            }
            const float4 bp4 = ((const float4*)(base_e_g + lb * NE))[t];
            bn[0] = bp4.x; bn[1] = bp4.y; bn[2] = bp4.z; bn[3] = bp4.w;
        }

        // ---- owner gather: S for this layer + beliefs/loss for layer l-1 ----
        {
            float S0 = 0.0f, S1 = 0.0f, bel0 = bias[0], bel1 = bias[1];
            #pragma unroll
            for (int jg = 0; jg < VG; ++jg) {
                float4 a = ((const float4*)s_cN)[jg * NN + t];
                S0   += a.x*wc0[jg*4+0] + a.y*wc0[jg*4+1] + a.z*wc0[jg*4+2] + a.w*wc0[jg*4+3];
                bel0 += a.x*mg0[jg*4+0] + a.y*mg0[jg*4+1] + a.z*mg0[jg*4+2] + a.w*mg0[jg*4+3];
                float4 c4 = ((const float4*)s_cN)[jg * NN + t + NT];
                S1   += c4.x*wc1[jg*4+0] + c4.y*wc1[jg*4+1] + c4.z*wc1[jg*4+2] + c4.w*wc1[jg*4+3];
                bel1 += c4.x*mg1[jg*4+0] + c4.y*mg1[jg*4+1] + c4.z*mg1[jg*4+2] + c4.w*mg1[jg*4+3];
            }
            s_S[t]      = S0;
            s_S[t + NT] = S1;
            if (l > 0) {
                const float rr = s_rho[l - 1];
                float sp0 = fmaxf(bel0, 0.0f) + __logf(1.0f + __expf(-fabsf(bel0)));
                float sp1 = fmaxf(bel1, 0.0f) + __logf(1.0f + __expf(-fabsf(bel1)));
                loss += rr * ((sp0 - omeg[0] * bel0) + (sp1 - omeg[1] * bel1));
            }
        }
        __syncthreads();   // barrier A: s_S ready; old s_cN fully consumed

        const float rw_ = s_rw[l];

        // ---- check-node update over this thread's 4 edges ----
        float d[HE];
        #pragma unroll
        for (int k = 0; k < HE; ++k) {
            float te = bc[k] + s_S[col[k]] - msg[k];
            float e  = __expf(te);                          // v_exp_f32
            float dd = 1.0f - 2.0f * __builtin_amdgcn_rcpf(e + 1.0f);
            dd = fminf(fmaxf(dd, -1.0f), 1.0f);             // guard rcp rounding
            if (dd == 0.0f) dd = 1.0f;                      // jnp.where(d==0,1,d)
            d[k] = dd;
        }
        float p01 = d[0] * d[1], p23 = d[2] * d[3];
        float p4  = p01 * p23;
        float pot = __shfl_xor(p4, 1, 64);                  // partner half's product
        float ptot = p4 * pot;                              // full row product

        #pragma unroll
        for (int k = 0; k < HE; ++k) {
            float x  = ptot * __builtin_amdgcn_rcpf(d[k]);  // reference's p/d
            float r  = (1.0f + x) * __builtin_amdgcn_rcpf(1.0f - x);
            float nm = sgn * __logf(r) + rw_ * msg[k];      // 2*atanh*sgn + res*msg
            msg[k] = nm;
            s_cN[esl[k]] = nm;                              // plain write to CSC slot
        }

        // rotate prefetched weights
        #pragma unroll
        for (int k = 0; k < HE; ++k) bc[k] = bn[k];
        #pragma unroll
        for (int j = 0; j < VP; ++j) { wc0[j] = wn0[j]; wc1[j] = wn1[j]; }

        __syncthreads();   // barrier B: s_cN complete for next layer's gather
    }

    // tail: loss for the last layer
    {
        const float rr = s_rho[LL - 1];
        float bel0 = bias[0], bel1 = bias[1];
        #pragma unroll
        for (int jg = 0; jg < VG; ++jg) {
            float4 a = ((const float4*)s_cN)[jg * NN + t];
            bel0 += a.x*mg0[jg*4+0] + a.y*mg0[jg*4+1] + a.z*mg0[jg*4+2] + a.w*mg0[jg*4+3];
            float4 c4 = ((const float4*)s_cN)[jg * NN + t + NT];
            bel1 += c4.x*mg1[jg*4+0] + c4.y*mg1[jg*4+1] + c4.z*mg1[jg*4+2] + c4.w*mg1[jg*4+3];
        }
        float sp0 = fmaxf(bel0, 0.0f) + __logf(1.0f + __expf(-fabsf(bel0)));
        float sp1 = fmaxf(bel1, 0.0f) + __logf(1.0f + __expf(-fabsf(bel1)));
        loss += rr * ((sp0 - omeg[0] * bel0) + (sp1 - omeg[1] * bel1));
    }

    // ---- block-wide loss reduction (12 waves) ----
    #pragma unroll
    for (int off = 32; off > 0; off >>= 1)
        loss += __shfl_down(loss, off, 64);
    int wave = t >> 6, lane = t & 63;
    if (lane == 0) s_red[wave] = loss;
    __syncthreads();
    if (t == 0) {
        float tot = 0.0f;
        #pragma unroll
        for (int w = 0; w < 12; ++w) tot += s_red[w];
        atomicAdd(out, tot * (1.0f / (float)MB));
    }
}

// ---------------------------------------------------------------------------
extern "C" void kernel_launch(void* const* d_in, const int* in_sizes, int n_in,
                              void* d_out, int out_size, void* d_ws, size_t ws_size,
                              hipStream_t stream) {
    const float* synd     = (const float*)d_in[0];
    const float* errors   = (const float*)d_in[1];
    const float* H        = (const float*)d_in[2];
    const float* llrs     = (const float*)d_in[3];
    const float* w_de     = (const float*)d_in[4];
    const float* w_llr    = (const float*)d_in[5];
    const float* marg_de  = (const float*)d_in[6];
    const float* marg_llr = (const float*)d_in[7];
    const float* res_w    = (const float*)d_in[8];
    const float* rhos     = (const float*)d_in[9];
    float* out = (float*)d_out;

    // Workspace layout (4-byte elements). Zeroed region first (contiguous):
    //   wde_vT  L*VG*NN*4 = 368640
    //   marg_vT VG*NN*4   =  18432
    //   gcnt    NN        =   1536   -> zero block = 388608 elements
    // then base_e L*NE = 61440, col_pack NE = 3072.  Total ~1.73 MB.
    float* wde_vT  = (float*)d_ws;
    float* marg_vT = wde_vT + (size_t)LL * VG * NN * 4;
    int*   gcnt    = (int*)(marg_vT + VG * NN * 4);
    float* base_e  = (float*)(gcnt + NN);
    int*   col_pack= (int*)(base_e + (size_t)LL * NE);
    const int nzero = LL * VG * NN * 4 + VG * NN * 4 + NN;

    zero_kernel<<<512, 256, 0, stream>>>(wde_vT, nzero, out);
    setup_kernel<<<MM, 256, 0, stream>>>(H, llrs, w_llr, w_de, marg_de,
                                         col_pack, base_e, wde_vT, marg_vT, gcnt);
    bp_kernel<<<MB, NT, 0, stream>>>(synd, errors, llrs, marg_llr, res_w, rhos,
                                     col_pack, base_e, wde_vT, marg_vT, out);
}

// Round 13
// 145.372 us; speedup vs baseline: 1.0411x; 1.0411x over previous
//
#include <hip/hip_runtime.h>
#include <math.h>

// Problem constants (match reference)
#define MB 8      // batch
#define MM 384    // checks
#define NN 1536   // variables
#define LL 20     // layers
#define RW 8      // row weight of H
#define HE 4      // edges per thread (half row)
#define NE (MM*RW)  // 3072 edges
#define NT 768    // bp block size (2 threads per check row)
#define VP 12     // max column degree supported (validated R10-R12: absmax=0)
#define VG 3      // VP/4 float4 groups

// ---------------------------------------------------------------------------
// Fused setup: one block (256 thr = 4 waves) per check row.
//  4-wave ballot scan of H row m -> RW column indices; assign each edge its
//  CSC position via global column counters (gcnt pre-zeroed by memset);
//  fill transposed weight tables wde_vT[l][jg][n][ji], marg_vT[jg][n][ji].
//  NOTE: table PADDING is left as garbage — it only ever multiplies s_cN
//  padding slots, which bp keeps at exactly 0.0 (0 x finite = 0).
// ---------------------------------------------------------------------------
__global__ __launch_bounds__(256) void setup_kernel(
    const float* __restrict__ H,
    const float* __restrict__ llrs,
    const float* __restrict__ w_llr,
    const float* __restrict__ w_de,
    const float* __restrict__ marg_de,
    int*   __restrict__ col_pack,
    float* __restrict__ base_e,
    float* __restrict__ wde_vT,
    float* __restrict__ marg_vT,
    int*   __restrict__ gcnt,
    float* __restrict__ out) {
    const int m = blockIdx.x;
    const int t = threadIdx.x;
    const int w = t >> 6, lane = t & 63;
    __shared__ int s_qcol[4][RW];
    __shared__ int s_qcnt[4];
    __shared__ int s_col[RW];
    __shared__ int s_pos[RW];

    const float* row = H + (size_t)m * NN;
    int count = 0;
    for (int c0 = w * 384; c0 < (w + 1) * 384; c0 += 64) {
        float v = row[c0 + lane];
        unsigned long long mask = __ballot(v != 0.0f);
        if (v != 0.0f) {
            int pos = count + (int)__popcll(mask & ((1ull << lane) - 1ull));
            if (pos < RW) s_qcol[w][pos] = c0 + lane;
        }
        count += (int)__popcll(mask);
    }
    if (lane == 0) s_qcnt[w] = (count < RW) ? count : RW;
    __syncthreads();
    if (t == 0) {
        int off = 0;
        for (int q = 0; q < 4; ++q)
            for (int i = 0; i < s_qcnt[q]; ++i) {
                if (off < RW) s_col[off] = s_qcol[q][i];
                ++off;
            }
    }
    __syncthreads();

    if (t < RW) {
        int c = s_col[t];
        int pos = atomicAdd(&gcnt[c], 1);
        if (pos >= VP) pos = VP - 1;   // clamp (validated: never hit)
        s_pos[t] = pos;
        col_pack[m * RW + t] = c | (pos << 16);
        marg_vT[((pos >> 2) * NN + c) * 4 + (pos & 3)] = marg_de[m * NN + c];
    }
    if (m == 0 && t == 0) out[0] = 0.0f;
    __syncthreads();

    // 20 layers x 8 edges per row
    for (int idx = t; idx < LL * RW; idx += 256) {
        int l = idx >> 3;
        int k = idx & 7;
        int c = s_col[k];
        int pos = s_pos[k];
        wde_vT[((l * VG + (pos >> 2)) * NN + c) * 4 + (pos & 3)] =
            w_de[(size_t)l * MM * NN + (size_t)m * NN + c];
        base_e[l * NE + m * RW + k] = llrs[c] * w_llr[l * NN + c];
    }
}

// ===========================================================================
// One full layer body as a macro so the x2-unrolled loop can swap register
// sets (kills the 28-mov rotation). WCx = current weights, WNx = next
// (prefetched into), BC/BN = current/next base_e.
// ===========================================================================
#define LAYER_BODY(lv, WC0, WC1, BC, WN0, WN1, BN)                            \
{                                                                             \
    /* prefetch next layer's wde_vT and base_e */                             \
    {                                                                         \
        int lb = ((lv) + 1 < LL) ? ((lv) + 1) : (LL - 1);                     \
        _Pragma("unroll")                                                     \
        for (int jg = 0; jg < VG; ++jg) {                                     \
            float4 a = ((const float4*)wde_vT)[(lb * VG + jg) * NN + t];      \
            WN0[jg*4+0]=a.x; WN0[jg*4+1]=a.y; WN0[jg*4+2]=a.z; WN0[jg*4+3]=a.w; \
            float4 c4 = ((const float4*)wde_vT)[(lb * VG + jg) * NN + t + NT];\
            WN1[jg*4+0]=c4.x; WN1[jg*4+1]=c4.y; WN1[jg*4+2]=c4.z; WN1[jg*4+3]=c4.w; \
        }                                                                     \
        const float4 bp4 = ((const float4*)(base_e_g + lb * NE))[t];          \
        BN[0]=bp4.x; BN[1]=bp4.y; BN[2]=bp4.z; BN[3]=bp4.w;                   \
    }                                                                         \
    /* owner gather: S for this layer + beliefs/loss for layer lv-1 */        \
    {                                                                         \
        float S0 = 0.0f, S1 = 0.0f, bel0 = bias[0], bel1 = bias[1];           \
        _Pragma("unroll")                                                     \
        for (int jg = 0; jg < VG; ++jg) {                                     \
            float4 a = ((const float4*)s_cN)[jg * NN + t];                    \
            S0   += a.x*WC0[jg*4+0] + a.y*WC0[jg*4+1] + a.z*WC0[jg*4+2] + a.w*WC0[jg*4+3]; \
            bel0 += a.x*mg0[jg*4+0] + a.y*mg0[jg*4+1] + a.z*mg0[jg*4+2] + a.w*mg0[jg*4+3]; \
            float4 c4 = ((const float4*)s_cN)[jg * NN + t + NT];              \
            S1   += c4.x*WC1[jg*4+0] + c4.y*WC1[jg*4+1] + c4.z*WC1[jg*4+2] + c4.w*WC1[jg*4+3]; \
            bel1 += c4.x*mg1[jg*4+0] + c4.y*mg1[jg*4+1] + c4.z*mg1[jg*4+2] + c4.w*mg1[jg*4+3]; \
        }                                                                     \
        s_S[t]      = S0;                                                     \
        s_S[t + NT] = S1;                                                     \
        if ((lv) > 0) {                                                       \
            const float rr = s_rho[(lv) - 1];                                 \
            float sp0 = fmaxf(bel0, 0.0f) + __logf(1.0f + __expf(-fabsf(bel0))); \
            float sp1 = fmaxf(bel1, 0.0f) + __logf(1.0f + __expf(-fabsf(bel1))); \
            loss += rr * ((sp0 - omeg[0] * bel0) + (sp1 - omeg[1] * bel1));   \
        }                                                                     \
    }                                                                         \
    __syncthreads();   /* barrier A */                                        \
    {                                                                         \
        const float rw_ = s_rw[(lv)];                                         \
        float d[HE];                                                          \
        _Pragma("unroll")                                                     \
        for (int k = 0; k < HE; ++k) {                                        \
            float te = BC[k] + s_S[col[k]] - msg[k];                          \
            float e  = __expf(te);                                            \
            float dd = 1.0f - 2.0f * __builtin_amdgcn_rcpf(e + 1.0f);         \
            dd = fminf(fmaxf(dd, -1.0f), 1.0f);                               \
            if (dd == 0.0f) dd = 1.0f;                                        \
            d[k] = dd;                                                        \
        }                                                                     \
        /* exclusion via prefix/suffix products (no divides) */               \
        float pre2 = d[0] * d[1];                                             \
        float suf1 = d[2] * d[3];                                             \
        float p4   = pre2 * suf1;                                             \
        float pot  = __shfl_xor(p4, 1, 64);                                   \
        float ex[HE];                                                         \
        ex[0] = d[1] * suf1;                                                  \
        ex[1] = d[0] * suf1;                                                  \
        ex[2] = pre2 * d[3];                                                  \
        ex[3] = pre2 * d[2];                                                  \
        _Pragma("unroll")                                                     \
        for (int k = 0; k < HE; ++k) {                                        \
            float x  = ex[k] * pot;                                           \
            float r  = (1.0f + x) * __builtin_amdgcn_rcpf(1.0f - x);          \
            float nm = sgn * __logf(r) + rw_ * msg[k];                        \
            msg[k] = nm;                                                      \
            s_cN[esl[k]] = nm;                                                \
        }                                                                     \
    }                                                                         \
    __syncthreads();   /* barrier B */                                        \
}

// ---------------------------------------------------------------------------
// Main BP kernel: 8 blocks, 768 threads = 2 per check row (4 edges each).
// Zero atomics; CSC-padded LDS exchange array; 2 barriers/layer; layer loop
// unrolled x2 with swapped register sets (no weight-rotation movs).
// ---------------------------------------------------------------------------
__global__ __launch_bounds__(NT) void bp_kernel(
    const float* __restrict__ synd,       // (B,M,1)
    const float* __restrict__ errors,     // (B,N)
    const float* __restrict__ llrs,       // (N)
    const float* __restrict__ marg_llr,   // (N)
    const float* __restrict__ res_w,      // (L)
    const float* __restrict__ rhos,       // (L)
    const int*   __restrict__ col_pack,   // (E)  c | pos<<16
    const float* __restrict__ base_e_g,   // (L,E)
    const float* __restrict__ wde_vT,     // (L,VG,N,4)
    const float* __restrict__ marg_vT,    // (VG,N,4)
    float* __restrict__ out) {

    __shared__ float s_cN[NN * VP];       // 72 KB  edge messages, CSC-padded
    __shared__ float s_S[NN];             // 6 KB   variable sums
    __shared__ float s_rw[LL];
    __shared__ float s_rho[LL];
    __shared__ float s_red[12];

    const int b = blockIdx.x;
    const int t = threadIdx.x;
    const int m = t >> 1;        // check row

    // ---- per-edge register state ----
    int col[HE], esl[HE];
    {
        const int4 cp = ((const int4*)col_pack)[t];
        int v[HE] = {cp.x, cp.y, cp.z, cp.w};
        #pragma unroll
        for (int k = 0; k < HE; ++k) {
            int c = v[k] & 0xFFFF, pos = v[k] >> 16;
            col[k] = c;
            esl[k] = ((pos >> 2) * NN + c) * 4 + (pos & 3);
        }
    }
    float msg[HE] = {0.0f, 0.0f, 0.0f, 0.0f};
    const float sgn = 1.0f - 2.0f * synd[b * MM + m];

    float bias[2], omeg[2];
    #pragma unroll
    for (int i = 0; i < 2; ++i) {
        int n = t + i * NT;
        bias[i] = llrs[n] * marg_llr[n];
        omeg[i] = 1.0f - errors[b * NN + n];
    }

    // ---- register-held transposed weights for owned variables t, t+NT ----
    float mg0[VP], mg1[VP];
    #pragma unroll
    for (int jg = 0; jg < VG; ++jg) {
        float4 a = ((const float4*)marg_vT)[jg * NN + t];
        mg0[jg*4+0] = a.x; mg0[jg*4+1] = a.y; mg0[jg*4+2] = a.z; mg0[jg*4+3] = a.w;
        float4 c4 = ((const float4*)marg_vT)[jg * NN + t + NT];
        mg1[jg*4+0] = c4.x; mg1[jg*4+1] = c4.y; mg1[jg*4+2] = c4.z; mg1[jg*4+3] = c4.w;
    }
    float wcA0[VP], wcA1[VP], wcB0[VP], wcB1[VP];
    #pragma unroll
    for (int jg = 0; jg < VG; ++jg) {          // layer 0 -> A set
        float4 a = ((const float4*)wde_vT)[jg * NN + t];
        wcA0[jg*4+0] = a.x; wcA0[jg*4+1] = a.y; wcA0[jg*4+2] = a.z; wcA0[jg*4+3] = a.w;
        float4 c4 = ((const float4*)wde_vT)[jg * NN + t + NT];
        wcA1[jg*4+0] = c4.x; wcA1[jg*4+1] = c4.y; wcA1[jg*4+2] = c4.z; wcA1[jg*4+3] = c4.w;
    }
    float bcA[HE], bcB[HE];
    {
        const float4 bp4 = ((const float4*)base_e_g)[t];   // layer 0
        bcA[0] = bp4.x; bcA[1] = bp4.y; bcA[2] = bp4.z; bcA[3] = bp4.w;
    }

    // ---- zero the exchange array (padding slots stay 0 forever) ----
    #pragma unroll
    for (int j = 0; j < 6; ++j)
        ((float4*)s_cN)[j * NT + t] = make_float4(0.f, 0.f, 0.f, 0.f);
    if (t < LL) { s_rw[t] = res_w[t]; s_rho[t] = rhos[t]; }

    float loss = 0.0f;
    __syncthreads();

    // ---- layer loop, unrolled x2 with A/B register-set swap ----
    for (int l = 0; l < LL; l += 2) {
        LAYER_BODY(l,     wcA0, wcA1, bcA, wcB0, wcB1, bcB);
        LAYER_BODY(l + 1, wcB0, wcB1, bcB, wcA0, wcA1, bcA);
    }

    // tail: loss for the last layer
    {
        const float rr = s_rho[LL - 1];
        float bel0 = bias[0], bel1 = bias[1];
        #pragma unroll
        for (int jg = 0; jg < VG; ++jg) {
            float4 a = ((const float4*)s_cN)[jg * NN + t];
            bel0 += a.x*mg0[jg*4+0] + a.y*mg0[jg*4+1] + a.z*mg0[jg*4+2] + a.w*mg0[jg*4+3];
            float4 c4 = ((const float4*)s_cN)[jg * NN + t + NT];
            bel1 += c4.x*mg1[jg*4+0] + c4.y*mg1[jg*4+1] + c4.z*mg1[jg*4+2] + c4.w*mg1[jg*4+3];
        }
        float sp0 = fmaxf(bel0, 0.0f) + __logf(1.0f + __expf(-fabsf(bel0)));
        float sp1 = fmaxf(bel1, 0.0f) + __logf(1.0f + __expf(-fabsf(bel1)));
        loss += rr * ((sp0 - omeg[0] * bel0) + (sp1 - omeg[1] * bel1));
    }

    // ---- block-wide loss reduction (12 waves) ----
    #pragma unroll
    for (int off = 32; off > 0; off >>= 1)
        loss += __shfl_down(loss, off, 64);
    int wave = t >> 6, lane = t & 63;
    if (lane == 0) s_red[wave] = loss;
    __syncthreads();
    if (t == 0) {
        float tot = 0.0f;
        #pragma unroll
        for (int w = 0; w < 12; ++w) tot += s_red[w];
        atomicAdd(out, tot * (1.0f / (float)MB));
    }
}

// ---------------------------------------------------------------------------
extern "C" void kernel_launch(void* const* d_in, const int* in_sizes, int n_in,
                              void* d_out, int out_size, void* d_ws, size_t ws_size,
                              hipStream_t stream) {
    const float* synd     = (const float*)d_in[0];
    const float* errors   = (const float*)d_in[1];
    const float* H        = (const float*)d_in[2];
    const float* llrs     = (const float*)d_in[3];
    const float* w_de     = (const float*)d_in[4];
    const float* w_llr    = (const float*)d_in[5];
    const float* marg_de  = (const float*)d_in[6];
    const float* marg_llr = (const float*)d_in[7];
    const float* res_w    = (const float*)d_in[8];
    const float* rhos     = (const float*)d_in[9];
    float* out = (float*)d_out;

    // Workspace layout (4-byte elements):
    //   wde_vT  L*VG*NN*4   (padding garbage-safe: pairs with s_cN zeros)
    //   marg_vT VG*NN*4     (padding garbage-safe)
    //   gcnt    NN          (memset to 0 below)
    //   base_e  L*NE
    //   col_pack NE
    float* wde_vT  = (float*)d_ws;
    float* marg_vT = wde_vT + (size_t)LL * VG * NN * 4;
    int*   gcnt    = (int*)(marg_vT + VG * NN * 4);
    float* base_e  = (float*)(gcnt + NN);
    int*   col_pack= (int*)(base_e + (size_t)LL * NE);

    hipMemsetAsync(gcnt, 0, NN * sizeof(int), stream);
    setup_kernel<<<MM, 256, 0, stream>>>(H, llrs, w_llr, w_de, marg_de,
                                         col_pack, base_e, wde_vT, marg_vT,
                                         gcnt, out);
    bp_kernel<<<MB, NT, 0, stream>>>(synd, errors, llrs, marg_llr, res_w, rhos,
                                     col_pack, base_e, wde_vT, marg_vT, out);
}

// Round 14
// 144.832 us; speedup vs baseline: 1.0450x; 1.0037x over previous
//
#include <hip/hip_runtime.h>
#include <math.h>

// Problem constants (match reference)
#define MB 8      // batch
#define MM 384    // checks
#define NN 1536   // variables
#define LL 20     // layers
#define RW 8      // row weight of H
#define HE 4      // edges per thread (half row)
#define NE (MM*RW)  // 3072 edges
#define NT 768    // bp block size (2 threads per check row)
#define VP 12     // max column degree supported (validated R10-R13: absmax=0)
#define VG 3      // VP/4 float4 groups

// Soft barrier: LDS visibility only (s_waitcnt lgkmcnt(0) + s_barrier).
// Deliberately does NOT drain vmcnt — the global wde_vT/base_e prefetches
// stay in flight across the barrier; hardware waitcnt protects their
// first register use. (__syncthreads would force vmcnt(0) every barrier.)
#define SOFT_BAR() asm volatile("s_waitcnt lgkmcnt(0)\n\ts_barrier" ::: "memory")

// ---------------------------------------------------------------------------
// Fused setup: one block (256 thr = 4 waves) per check row (unchanged R13).
// ---------------------------------------------------------------------------
__global__ __launch_bounds__(256) void setup_kernel(
    const float* __restrict__ H,
    const float* __restrict__ llrs,
    const float* __restrict__ w_llr,
    const float* __restrict__ w_de,
    const float* __restrict__ marg_de,
    int*   __restrict__ col_pack,
    float* __restrict__ base_e,
    float* __restrict__ wde_vT,
    float* __restrict__ marg_vT,
    int*   __restrict__ gcnt,
    float* __restrict__ out) {
    const int m = blockIdx.x;
    const int t = threadIdx.x;
    const int w = t >> 6, lane = t & 63;
    __shared__ int s_qcol[4][RW];
    __shared__ int s_qcnt[4];
    __shared__ int s_col[RW];
    __shared__ int s_pos[RW];

    const float* row = H + (size_t)m * NN;
    int count = 0;
    for (int c0 = w * 384; c0 < (w + 1) * 384; c0 += 64) {
        float v = row[c0 + lane];
        unsigned long long mask = __ballot(v != 0.0f);
        if (v != 0.0f) {
            int pos = count + (int)__popcll(mask & ((1ull << lane) - 1ull));
            if (pos < RW) s_qcol[w][pos] = c0 + lane;
        }
        count += (int)__popcll(mask);
    }
    if (lane == 0) s_qcnt[w] = (count < RW) ? count : RW;
    __syncthreads();
    if (t == 0) {
        int off = 0;
        for (int q = 0; q < 4; ++q)
            for (int i = 0; i < s_qcnt[q]; ++i) {
                if (off < RW) s_col[off] = s_qcol[q][i];
                ++off;
            }
    }
    __syncthreads();

    if (t < RW) {
        int c = s_col[t];
        int pos = atomicAdd(&gcnt[c], 1);
        if (pos >= VP) pos = VP - 1;   // clamp (validated: never hit)
        s_pos[t] = pos;
        col_pack[m * RW + t] = c | (pos << 16);
        marg_vT[((pos >> 2) * NN + c) * 4 + (pos & 3)] = marg_de[m * NN + c];
    }
    if (m == 0 && t == 0) out[0] = 0.0f;
    __syncthreads();

    for (int idx = t; idx < LL * RW; idx += 256) {
        int l = idx >> 3;
        int k = idx & 7;
        int c = s_col[k];
        int pos = s_pos[k];
        wde_vT[((l * VG + (pos >> 2)) * NN + c) * 4 + (pos & 3)] =
            w_de[(size_t)l * MM * NN + (size_t)m * NN + c];
        base_e[l * NE + m * RW + k] = llrs[c] * w_llr[l * NN + c];
    }
}

// ===========================================================================
// One full layer body (x2-unrolled register-set swap, as R13) — barriers are
// now SOFT (lgkmcnt-only), so the global prefetches survive across them.
// ===========================================================================
#define LAYER_BODY(lv, WC0, WC1, BC, WN0, WN1, BN)                            \
{                                                                             \
    /* prefetch next layer's wde_vT and base_e (stays in flight) */           \
    {                                                                         \
        int lb = ((lv) + 1 < LL) ? ((lv) + 1) : (LL - 1);                     \
        _Pragma("unroll")                                                     \
        for (int jg = 0; jg < VG; ++jg) {                                     \
            float4 a = ((const float4*)wde_vT)[(lb * VG + jg) * NN + t];      \
            WN0[jg*4+0]=a.x; WN0[jg*4+1]=a.y; WN0[jg*4+2]=a.z; WN0[jg*4+3]=a.w; \
            float4 c4 = ((const float4*)wde_vT)[(lb * VG + jg) * NN + t + NT];\
            WN1[jg*4+0]=c4.x; WN1[jg*4+1]=c4.y; WN1[jg*4+2]=c4.z; WN1[jg*4+3]=c4.w; \
        }                                                                     \
        const float4 bp4 = ((const float4*)(base_e_g + lb * NE))[t];          \
        BN[0]=bp4.x; BN[1]=bp4.y; BN[2]=bp4.z; BN[3]=bp4.w;                   \
    }                                                                         \
    /* owner gather: S for this layer + beliefs/loss for layer lv-1 */        \
    {                                                                         \
        float S0 = 0.0f, S1 = 0.0f, bel0 = bias[0], bel1 = bias[1];           \
        _Pragma("unroll")                                                     \
        for (int jg = 0; jg < VG; ++jg) {                                     \
            float4 a = ((const float4*)s_cN)[jg * NN + t];                    \
            S0   += a.x*WC0[jg*4+0] + a.y*WC0[jg*4+1] + a.z*WC0[jg*4+2] + a.w*WC0[jg*4+3]; \
            bel0 += a.x*mg0[jg*4+0] + a.y*mg0[jg*4+1] + a.z*mg0[jg*4+2] + a.w*mg0[jg*4+3]; \
            float4 c4 = ((const float4*)s_cN)[jg * NN + t + NT];              \
            S1   += c4.x*WC1[jg*4+0] + c4.y*WC1[jg*4+1] + c4.z*WC1[jg*4+2] + c4.w*WC1[jg*4+3]; \
            bel1 += c4.x*mg1[jg*4+0] + c4.y*mg1[jg*4+1] + c4.z*mg1[jg*4+2] + c4.w*mg1[jg*4+3]; \
        }                                                                     \
        s_S[t]      = S0;                                                     \
        s_S[t + NT] = S1;                                                     \
        if ((lv) > 0) {                                                       \
            const float rr = s_rho[(lv) - 1];                                 \
            float sp0 = fmaxf(bel0, 0.0f) + __logf(1.0f + __expf(-fabsf(bel0))); \
            float sp1 = fmaxf(bel1, 0.0f) + __logf(1.0f + __expf(-fabsf(bel1))); \
            loss += rr * ((sp0 - omeg[0] * bel0) + (sp1 - omeg[1] * bel1));   \
        }                                                                     \
    }                                                                         \
    SOFT_BAR();   /* barrier A: s_S visible; old s_cN consumed */             \
    {                                                                         \
        const float rw_ = s_rw[(lv)];                                         \
        float d[HE];                                                          \
        _Pragma("unroll")                                                     \
        for (int k = 0; k < HE; ++k) {                                        \
            float te = BC[k] + s_S[col[k]] - msg[k];                          \
            float e  = __expf(te);                                            \
            float dd = 1.0f - 2.0f * __builtin_amdgcn_rcpf(e + 1.0f);         \
            dd = fminf(fmaxf(dd, -1.0f), 1.0f);                               \
            if (dd == 0.0f) dd = 1.0f;                                        \
            d[k] = dd;                                                        \
        }                                                                     \
        float pre2 = d[0] * d[1];                                             \
        float suf1 = d[2] * d[3];                                             \
        float p4   = pre2 * suf1;                                             \
        float pot  = __shfl_xor(p4, 1, 64);                                   \
        float ex[HE];                                                         \
        ex[0] = d[1] * suf1;                                                  \
        ex[1] = d[0] * suf1;                                                  \
        ex[2] = pre2 * d[3];                                                  \
        ex[3] = pre2 * d[2];                                                  \
        _Pragma("unroll")                                                     \
        for (int k = 0; k < HE; ++k) {                                        \
            float x  = ex[k] * pot;                                           \
            float r  = (1.0f + x) * __builtin_amdgcn_rcpf(1.0f - x);          \
            float nm = sgn * __logf(r) + rw_ * msg[k];                        \
            msg[k] = nm;                                                      \
            s_cN[esl[k]] = nm;                                                \
        }                                                                     \
    }                                                                         \
    SOFT_BAR();   /* barrier B: s_cN visible for next gather */               \
}

// ---------------------------------------------------------------------------
// Main BP kernel: 8 blocks, 768 threads = 2 per check row (4 edges each).
// Zero atomics; CSC-padded LDS exchange; 2 SOFT barriers/layer; x2 unroll.
// ---------------------------------------------------------------------------
__global__ __launch_bounds__(NT) void bp_kernel(
    const float* __restrict__ synd,       // (B,M,1)
    const float* __restrict__ errors,     // (B,N)
    const float* __restrict__ llrs,       // (N)
    const float* __restrict__ marg_llr,   // (N)
    const float* __restrict__ res_w,      // (L)
    const float* __restrict__ rhos,       // (L)
    const int*   __restrict__ col_pack,   // (E)  c | pos<<16
    const float* __restrict__ base_e_g,   // (L,E)
    const float* __restrict__ wde_vT,     // (L,VG,N,4)
    const float* __restrict__ marg_vT,    // (VG,N,4)
    float* __restrict__ out) {

    __shared__ float s_cN[NN * VP];       // 72 KB  edge messages, CSC-padded
    __shared__ float s_S[NN];             // 6 KB   variable sums
    __shared__ float s_rw[LL];
    __shared__ float s_rho[LL];
    __shared__ float s_red[12];

    const int b = blockIdx.x;
    const int t = threadIdx.x;
    const int m = t >> 1;        // check row

    // ---- per-edge register state ----
    int col[HE], esl[HE];
    {
        const int4 cp = ((const int4*)col_pack)[t];
        int v[HE] = {cp.x, cp.y, cp.z, cp.w};
        #pragma unroll
        for (int k = 0; k < HE; ++k) {
            int c = v[k] & 0xFFFF, pos = v[k] >> 16;
            col[k] = c;
            esl[k] = ((pos >> 2) * NN + c) * 4 + (pos & 3);
        }
    }
    float msg[HE] = {0.0f, 0.0f, 0.0f, 0.0f};
    const float sgn = 1.0f - 2.0f * synd[b * MM + m];

    float bias[2], omeg[2];
    #pragma unroll
    for (int i = 0; i < 2; ++i) {
        int n = t + i * NT;
        bias[i] = llrs[n] * marg_llr[n];
        omeg[i] = 1.0f - errors[b * NN + n];
    }

    // ---- register-held transposed weights for owned variables t, t+NT ----
    float mg0[VP], mg1[VP];
    #pragma unroll
    for (int jg = 0; jg < VG; ++jg) {
        float4 a = ((const float4*)marg_vT)[jg * NN + t];
        mg0[jg*4+0] = a.x; mg0[jg*4+1] = a.y; mg0[jg*4+2] = a.z; mg0[jg*4+3] = a.w;
        float4 c4 = ((const float4*)marg_vT)[jg * NN + t + NT];
        mg1[jg*4+0] = c4.x; mg1[jg*4+1] = c4.y; mg1[jg*4+2] = c4.z; mg1[jg*4+3] = c4.w;
    }
    float wcA0[VP], wcA1[VP], wcB0[VP], wcB1[VP];
    #pragma unroll
    for (int jg = 0; jg < VG; ++jg) {          // layer 0 -> A set
        float4 a = ((const float4*)wde_vT)[jg * NN + t];
        wcA0[jg*4+0] = a.x; wcA0[jg*4+1] = a.y; wcA0[jg*4+2] = a.z; wcA0[jg*4+3] = a.w;
        float4 c4 = ((const float4*)wde_vT)[jg * NN + t + NT];
        wcA1[jg*4+0] = c4.x; wcA1[jg*4+1] = c4.y; wcA1[jg*4+2] = c4.z; wcA1[jg*4+3] = c4.w;
    }
    float bcA[HE], bcB[HE];
    {
        const float4 bp4 = ((const float4*)base_e_g)[t];   // layer 0
        bcA[0] = bp4.x; bcA[1] = bp4.y; bcA[2] = bp4.z; bcA[3] = bp4.w;
    }

    // ---- zero the exchange array (padding slots stay 0 forever) ----
    #pragma unroll
    for (int j = 0; j < 6; ++j)
        ((float4*)s_cN)[j * NT + t] = make_float4(0.f, 0.f, 0.f, 0.f);
    if (t < LL) { s_rw[t] = res_w[t]; s_rho[t] = rhos[t]; }

    float loss = 0.0f;
    __syncthreads();

    // ---- layer loop, unrolled x2 with A/B register-set swap ----
    for (int l = 0; l < LL; l += 2) {
        LAYER_BODY(l,     wcA0, wcA1, bcA, wcB0, wcB1, bcB);
        LAYER_BODY(l + 1, wcB0, wcB1, bcB, wcA0, wcA1, bcA);
    }

    // tail: loss for the last layer
    {
        const float rr = s_rho[LL - 1];
        float bel0 = bias[0], bel1 = bias[1];
        #pragma unroll
        for (int jg = 0; jg < VG; ++jg) {
            float4 a = ((const float4*)s_cN)[jg * NN + t];
            bel0 += a.x*mg0[jg*4+0] + a.y*mg0[jg*4+1] + a.z*mg0[jg*4+2] + a.w*mg0[jg*4+3];
            float4 c4 = ((const float4*)s_cN)[jg * NN + t + NT];
            bel1 += c4.x*mg1[jg*4+0] + c4.y*mg1[jg*4+1] + c4.z*mg1[jg*4+2] + c4.w*mg1[jg*4+3];
        }
        float sp0 = fmaxf(bel0, 0.0f) + __logf(1.0f + __expf(-fabsf(bel0)));
        float sp1 = fmaxf(bel1, 0.0f) + __logf(1.0f + __expf(-fabsf(bel1)));
        loss += rr * ((sp0 - omeg[0] * bel0) + (sp1 - omeg[1] * bel1));
    }

    // ---- block-wide loss reduction (12 waves) ----
    #pragma unroll
    for (int off = 32; off > 0; off >>= 1)
        loss += __shfl_down(loss, off, 64);
    int wave = t >> 6, lane = t & 63;
    if (lane == 0) s_red[wave] = loss;
    __syncthreads();
    if (t == 0) {
        float tot = 0.0f;
        #pragma unroll
        for (int w = 0; w < 12; ++w) tot += s_red[w];
        atomicAdd(out, tot * (1.0f / (float)MB));
    }
}

// ---------------------------------------------------------------------------
extern "C" void kernel_launch(void* const* d_in, const int* in_sizes, int n_in,
                              void* d_out, int out_size, void* d_ws, size_t ws_size,
                              hipStream_t stream) {
    const float* synd     = (const float*)d_in[0];
    const float* errors   = (const float*)d_in[1];
    const float* H        = (const float*)d_in[2];
    const float* llrs     = (const float*)d_in[3];
    const float* w_de     = (const float*)d_in[4];
    const float* w_llr    = (const float*)d_in[5];
    const float* marg_de  = (const float*)d_in[6];
    const float* marg_llr = (const float*)d_in[7];
    const float* res_w    = (const float*)d_in[8];
    const float* rhos     = (const float*)d_in[9];
    float* out = (float*)d_out;

    float* wde_vT  = (float*)d_ws;
    float* marg_vT = wde_vT + (size_t)LL * VG * NN * 4;
    int*   gcnt    = (int*)(marg_vT + VG * NN * 4);
    float* base_e  = (float*)(gcnt + NN);
    int*   col_pack= (int*)(base_e + (size_t)LL * NE);

    hipMemsetAsync(gcnt, 0, NN * sizeof(int), stream);
    setup_kernel<<<MM, 256, 0, stream>>>(H, llrs, w_llr, w_de, marg_de,
                                         col_pack, base_e, wde_vT, marg_vT,
                                         gcnt, out);
    bp_kernel<<<MB, NT, 0, stream>>>(synd, errors, llrs, marg_llr, res_w, rhos,
                                     col_pack, base_e, wde_vT, marg_vT, out);
}